// Round 6
// baseline (357.926 us; speedup 1.0000x reference)
//
#include <hip/hip_runtime.h>

// DeltaQuantLinear: out[t,o] = sum_k x[t,k] * (base[o,k] + (q[o,k]-zp[o])*scale[o]) + bias[o]
// M=8 tokens, N=11008 out rows, K=4096. Memory-bound: 361 MB (w+q) per call.
//
// Occupancy experiment on the PROVEN main loop: RPB 8->4 cuts live VGPRs
// (~170 -> ~115) into the <=128 band, so __launch_bounds__(256,4) yields
// 4 blocks/CU (16 waves/CU) instead of 2 (8 waves/CU). Per-wave load pattern
// unchanged: 8 nontemporal dwordx4 (w,q) in flight per row-group + 8 x loads.
// Reduction: single pass (32 outputs), 2 barriers (was 5).

#define IN_F    4096
#define OUT_F   11008
#define TOKENS  8
#define RPB     4                 // output rows per block
#define THREADS 256
#define NBLOCKS (OUT_F / RPB)     // 2752

typedef float vf4 __attribute__((ext_vector_type(4)));
typedef int   vi4 __attribute__((ext_vector_type(4)));

__global__ __launch_bounds__(THREADS, 4)
void DeltaQuantLinear_87540023427416_kernel(
    const float* __restrict__ x,      // [8, 4096]
    const float* __restrict__ w,      // [11008, 4096]
    const int*   __restrict__ q,      // [11008, 4096]
    const float* __restrict__ scales, // [11008]
    const float* __restrict__ zps,    // [11008]
    const float* __restrict__ bias,   // [11008]
    float*       __restrict__ out)    // [8, 11008]
{
    // reduction scratch: 32 outputs x 256 thread-partials, stride 257 (conflict-free)
    __shared__ float lds[32 * 257];   // 32,896 B
    __shared__ float lds2[32 * 8];    // 1,024 B  -> total 33.9 KB, 4 blocks/CU = 136 KB < 160

    const int tid = threadIdx.x;
    const int o0  = blockIdx.x * RPB;

    // per-row dequant constants (block-uniform -> scalar loads)
    float s[RPB], c0[RPB];
#pragma unroll
    for (int r = 0; r < RPB; ++r) {
        const float sc = scales[o0 + r];
        s[r]  = sc;
        c0[r] = -zps[o0 + r] * sc;   // (q - zp)*s = q*s + c0
    }

    float acc[RPB][TOKENS];
#pragma unroll
    for (int r = 0; r < RPB; ++r)
#pragma unroll
        for (int t = 0; t < TOKENS; ++t) acc[r][t] = 0.0f;

    // Thread owns k = c*1024 + tid*4 + j (j in 0..3), c in 0..3.
    // Per wave: contiguous 1 KB dwordx4 loads for x, w, q.
#pragma unroll
    for (int c = 0; c < 4; ++c) {
        const int kbase = c * 1024 + tid * 4;

        vf4 xr[TOKENS];
#pragma unroll
        for (int t = 0; t < TOKENS; ++t)
            xr[t] = *(const vf4*)(x + t * IN_F + kbase);

        // 4 rows in one group: 8 NT loads in flight (same per-wave depth as proven kernel)
        vf4 wv[RPB];
        vi4 qv[RPB];
#pragma unroll
        for (int r = 0; r < RPB; ++r) {
            const float* wp = w + (size_t)(o0 + r) * IN_F + kbase;
            const int*   qp = q + (size_t)(o0 + r) * IN_F + kbase;
            wv[r] = __builtin_nontemporal_load((const vf4*)wp);
            qv[r] = __builtin_nontemporal_load((const vi4*)qp);
        }
#pragma unroll
        for (int r = 0; r < RPB; ++r) {
#pragma unroll
            for (int j = 0; j < 4; ++j) {
                const float wfull = fmaf((float)qv[r][j], s[r], wv[r][j] + c0[r]);
#pragma unroll
                for (int t = 0; t < TOKENS; ++t)
                    acc[r][t] = fmaf(xr[t][j], wfull, acc[r][t]);
            }
        }
    }

    // Block reduction: 32 outputs (4 rows x 8 tokens), 256 partials each. Single pass.
#pragma unroll
    for (int r = 0; r < RPB; ++r)
#pragma unroll
        for (int t = 0; t < TOKENS; ++t)
            lds[(r * 8 + t) * 257 + tid] = acc[r][t];
    __syncthreads();

    {   // 8 threads per output, each sums 32 partials (conflict-free: stride-257 rows)
        const int l = tid & 31;       // output index
        const int p = tid >> 5;       // partial group
        float sum = 0.0f;
        const float* row = &lds[l * 257 + p * 32];
#pragma unroll
        for (int j = 0; j < 32; ++j) sum += row[j];
        lds2[l * 8 + p] = sum;
    }
    __syncthreads();

    if (tid < 32) {
        float tot = 0.0f;
#pragma unroll
        for (int j = 0; j < 8; ++j) tot += lds2[tid * 8 + j];
        const int r = tid >> 3;
        const int t = tid & 7;
        const int o = o0 + r;
        out[t * OUT_F + o] = tot + bias[o];
    }
}

extern "C" void kernel_launch(void* const* d_in, const int* in_sizes, int n_in,
                              void* d_out, int out_size, void* d_ws, size_t ws_size,
                              hipStream_t stream) {
    const float* x      = (const float*)d_in[0];
    const float* w      = (const float*)d_in[1];
    const int*   q      = (const int*)d_in[2];
    const float* scales = (const float*)d_in[3];
    const float* zps    = (const float*)d_in[4];
    const float* bias   = (const float*)d_in[5];
    float* out = (float*)d_out;

    DeltaQuantLinear_87540023427416_kernel<<<NBLOCKS, THREADS, 0, stream>>>(
        x, w, q, scales, zps, bias, out);
}

// Round 8
// 336.893 us; speedup vs baseline: 1.0624x; 1.0624x over previous
//
#include <hip/hip_runtime.h>

// DeltaQuantLinear: out[t,o] = sum_k x[t,k] * (base[o,k] + (q[o,k]-zp[o])*scale[o]) + bias[o]
// M=8 tokens, N=11008 out rows, K=4096. Memory-bound: 361 MB weights+q per call.
//
// FINAL: proven structure (337.7 µs, reproduced twice). Tested and rejected:
//   - wave-per-block / no barriers (R2): +31.7 µs (register-budget loss > barrier cost)
//   - RPB=4 / 4 blocks/CU (R6): +20.2 µs (concurrency already saturated at 8 waves/CU;
//     doubled x traffic + per-block overhead)
// Kernel-proper <= 74 µs vs 53 µs read-roofline; harness fills run at only 84-86% peak.

#define IN_F    4096
#define OUT_F   11008
#define TOKENS  8
#define RPB     8                 // output rows per block
#define THREADS 256
#define NBLOCKS (OUT_F / RPB)     // 1376

// clang native vectors: accepted by __builtin_nontemporal_load (HIP_vector_type is not)
typedef float vf4 __attribute__((ext_vector_type(4)));
typedef int   vi4 __attribute__((ext_vector_type(4)));

__global__ __launch_bounds__(THREADS, 2)
void DeltaQuantLinear_87540023427416_kernel(
    const float* __restrict__ x,      // [8, 4096]
    const float* __restrict__ w,      // [11008, 4096]
    const int*   __restrict__ q,      // [11008, 4096]
    const float* __restrict__ scales, // [11008]
    const float* __restrict__ zps,    // [11008]
    const float* __restrict__ bias,   // [11008]
    float*       __restrict__ out)    // [8, 11008]
{
    // reduction scratch: 32 outputs x 256 thread-partials, stride 257 (conflict-free)
    __shared__ float lds[32 * 257];   // 32,896 B
    __shared__ float lds2[32 * 8];    // 1,024 B

    const int tid = threadIdx.x;
    const int o0  = blockIdx.x * RPB;

    // per-row dequant constants (block-uniform -> scalar loads)
    float s[RPB], c0[RPB];
#pragma unroll
    for (int r = 0; r < RPB; ++r) {
        const float sc = scales[o0 + r];
        s[r]  = sc;
        c0[r] = -zps[o0 + r] * sc;   // (q - zp)*s = q*s + c0
    }

    float acc[RPB][TOKENS];
#pragma unroll
    for (int r = 0; r < RPB; ++r)
#pragma unroll
        for (int t = 0; t < TOKENS; ++t) acc[r][t] = 0.0f;

    // Thread owns k = c*1024 + tid*4 + j  (j in 0..3), c in 0..3.
    // Per wave: contiguous 1 KB dwordx4 loads for x, w, q.
#pragma unroll
    for (int c = 0; c < 4; ++c) {
        const int kbase = c * 1024 + tid * 4;

        vf4 xr[TOKENS];
#pragma unroll
        for (int t = 0; t < TOKENS; ++t)
            xr[t] = *(const vf4*)(x + t * IN_F + kbase);

#pragma unroll
        for (int g = 0; g < 2; ++g) {   // rows in groups of 4: 8 loads in flight
            vf4 wv[4];
            vi4 qv[4];
#pragma unroll
            for (int rr = 0; rr < 4; ++rr) {
                const int r = g * 4 + rr;
                const float* wp = w + (size_t)(o0 + r) * IN_F + kbase;
                const int*   qp = q + (size_t)(o0 + r) * IN_F + kbase;
                wv[rr] = __builtin_nontemporal_load((const vf4*)wp);
                qv[rr] = __builtin_nontemporal_load((const vi4*)qp);
            }
#pragma unroll
            for (int rr = 0; rr < 4; ++rr) {
                const int r = g * 4 + rr;
#pragma unroll
                for (int j = 0; j < 4; ++j) {
                    const float wfull = fmaf((float)qv[rr][j], s[r], wv[rr][j] + c0[r]);
#pragma unroll
                    for (int t = 0; t < TOKENS; ++t) {
                        acc[r][t] = fmaf(xr[t][j], wfull, acc[r][t]);
                    }
                }
            }
        }
    }

    // Block reduction: 64 outputs (8 rows x 8 tokens), 256 partials each.
    // Two halves of 4 rows to keep LDS at 33 KB.
#pragma unroll
    for (int h = 0; h < 2; ++h) {
#pragma unroll
        for (int rl = 0; rl < 4; ++rl)
#pragma unroll
            for (int t = 0; t < TOKENS; ++t)
                lds[(rl * 8 + t) * 257 + tid] = acc[h * 4 + rl][t];
        __syncthreads();

        {   // 8 threads per output, each sums 32 partials (conflict-free: stride-257 rows)
            const int l = tid & 31;       // output index within half
            const int p = tid >> 5;       // partial group
            float sum = 0.0f;
            const float* row = &lds[l * 257 + p * 32];
#pragma unroll
            for (int j = 0; j < 32; ++j) sum += row[j];
            lds2[l * 8 + p] = sum;
        }
        __syncthreads();

        if (tid < 32) {
            float tot = 0.0f;
#pragma unroll
            for (int j = 0; j < 8; ++j) tot += lds2[tid * 8 + j];
            const int rl = tid >> 3;
            const int t  = tid & 7;
            const int o  = o0 + h * 4 + rl;
            out[t * OUT_F + o] = tot + bias[o];
        }
        __syncthreads();
    }
}

extern "C" void kernel_launch(void* const* d_in, const int* in_sizes, int n_in,
                              void* d_out, int out_size, void* d_ws, size_t ws_size,
                              hipStream_t stream) {
    const float* x      = (const float*)d_in[0];
    const float* w      = (const float*)d_in[1];
    const int*   q      = (const int*)d_in[2];
    const float* scales = (const float*)d_in[3];
    const float* zps    = (const float*)d_in[4];
    const float* bias   = (const float*)d_in[5];
    float* out = (float*)d_out;

    DeltaQuantLinear_87540023427416_kernel<<<NBLOCKS, THREADS, 0, stream>>>(
        x, w, q, scales, zps, bias, out);
}